// Round 3
// baseline (590.721 us; speedup 1.0000x reference)
//
#include <hip/hip_runtime.h>
#include <math.h>

#define B_ 4
#define C_ 256
#define HW_ 4096
#define G_ 8
#define H_ 4
#define DH_ 64
#define GRP_ELEMS (32 * HW_)             // 131072
#define NCHUNK 16
#define CHUNK_ELEMS (GRP_ELEMS / NCHUNK) // 8192
#define EPS 1e-5f

typedef __attribute__((ext_vector_type(8))) short short8;
typedef __attribute__((ext_vector_type(4))) float f32x4;

__device__ __forceinline__ ushort f2bf(float x) {
    unsigned u = __builtin_bit_cast(unsigned, x);
    u += 0x7FFFu + ((u >> 16) & 1u);
    return (ushort)(u >> 16);
}
__device__ __forceinline__ float bf2f(ushort h) {
    unsigned u = ((unsigned)h) << 16;
    return __builtin_bit_cast(float, u);
}

// workspace layout (float-slot offsets)
#define XN_SZ   (B_ * C_ * HW_)          // f32
#define QKV_SZ  (B_ * 3 * C_ * HW_)      // ushort count
#define ATT_SZ  (B_ * C_ * HW_)          // f32
#define QT_SZ   (B_ * C_ * HW_)          // ushort count

// ---------------- GroupNorm stage 1: deterministic partial sums -----------
__global__ __launch_bounds__(256) void gn_partial(const float* __restrict__ x,
                                                  float* __restrict__ part) {
    int bg = blockIdx.x >> 4;
    int chunk = blockIdx.x & 15;
    const float4* p = (const float4*)(x + (size_t)bg * GRP_ELEMS + (size_t)chunk * CHUNK_ELEMS);
    int t = threadIdx.x;
    float s = 0.f, ss = 0.f;
#pragma unroll
    for (int i = 0; i < 8; ++i) {
        float4 v = p[t + i * 256];
        s  += v.x + v.y + v.z + v.w;
        ss += v.x * v.x + v.y * v.y + v.z * v.z + v.w * v.w;
    }
#pragma unroll
    for (int off = 32; off; off >>= 1) {
        s  += __shfl_xor(s, off, 64);
        ss += __shfl_xor(ss, off, 64);
    }
    __shared__ float ls[8];
    int wave = t >> 6, lane = t & 63;
    if (lane == 0) { ls[wave * 2] = s; ls[wave * 2 + 1] = ss; }
    __syncthreads();
    if (t == 0) {
        float S = 0.f, SS = 0.f;
#pragma unroll
        for (int w = 0; w < 4; ++w) { S += ls[w * 2]; SS += ls[w * 2 + 1]; }
        part[(bg * 16 + chunk) * 2]     = S;
        part[(bg * 16 + chunk) * 2 + 1] = SS;
    }
}

// ---------------- GroupNorm stage 2: normalize ----------------------------
__global__ __launch_bounds__(256) void gn_norm(const float* __restrict__ x,
                                               const float* __restrict__ gamma,
                                               const float* __restrict__ beta,
                                               const float* __restrict__ part,
                                               float* __restrict__ xn) {
    int bc = blockIdx.x;
    int b = bc >> 8, ch = bc & 255;
    int g = ch >> 5;
    int bg = b * G_ + g;
    float S = 0.f, SS = 0.f;
#pragma unroll
    for (int i = 0; i < 16; ++i) {
        S  += part[(bg * 16 + i) * 2];
        SS += part[(bg * 16 + i) * 2 + 1];
    }
    float mean = S * (1.f / GRP_ELEMS);
    float var  = SS * (1.f / GRP_ELEMS) - mean * mean;
    float inv  = rsqrtf(var + EPS);
    float a  = inv * gamma[ch];
    float bb = beta[ch] - mean * a;
    const float4* xin = (const float4*)(x + (size_t)bc * HW_);
    float4* xo = (float4*)(xn + (size_t)bc * HW_);
    int t = threadIdx.x;
#pragma unroll
    for (int i = 0; i < 4; ++i) {
        float4 v = xin[t + i * 256];
        v.x = v.x * a + bb; v.y = v.y * a + bb;
        v.z = v.z * a + bb; v.w = v.w * a + bb;
        xo[t + i * 256] = v;
    }
}

// ---------------- fp32 tiled GEMM: Out[b] = W(MxK) @ X[b](K x HW) ----------
template <bool BIAS_RES, bool OUT_BF16>
__global__ __launch_bounds__(256) void gemm_wx(const float* __restrict__ W,
                                               const float* __restrict__ X,
                                               void* __restrict__ Out,
                                               const float* __restrict__ bias,
                                               const float* __restrict__ res,
                                               int M) {
    __shared__ float Ws[64][68];
    __shared__ float Xs[64][68];
    int b  = blockIdx.z;
    int m0 = blockIdx.y * 64;
    int n0 = blockIdx.x * 64;
    const float* Xb = X + (size_t)b * C_ * HW_;
    int t = threadIdx.x;
    int ti = t >> 4, tj = t & 15;
    float acc[4][4] = {};

    for (int kt = 0; kt < 4; ++kt) {
        {
            int row = t >> 4;
            int q4  = t & 15;
#pragma unroll
            for (int it = 0; it < 4; ++it) {
                int mm = row + 16 * it;
                float4 v = *(const float4*)(W + (size_t)(m0 + mm) * C_ + kt * 64 + q4 * 4);
                Ws[q4 * 4 + 0][mm] = v.x;
                Ws[q4 * 4 + 1][mm] = v.y;
                Ws[q4 * 4 + 2][mm] = v.z;
                Ws[q4 * 4 + 3][mm] = v.w;
                int kk = row + 16 * it;
                float4 xv = *(const float4*)(Xb + (size_t)(kt * 64 + kk) * HW_ + n0 + q4 * 4);
                *(float4*)&Xs[kk][q4 * 4] = xv;
            }
        }
        __syncthreads();
#pragma unroll 8
        for (int kk = 0; kk < 64; ++kk) {
            float4 wv = *(const float4*)&Ws[kk][ti * 4];
            float4 xv = *(const float4*)&Xs[kk][tj * 4];
            float wr[4] = {wv.x, wv.y, wv.z, wv.w};
            float xr[4] = {xv.x, xv.y, xv.z, xv.w};
#pragma unroll
            for (int r = 0; r < 4; ++r)
#pragma unroll
                for (int c = 0; c < 4; ++c)
                    acc[r][c] += wr[r] * xr[c];
        }
        __syncthreads();
    }
#pragma unroll
    for (int r = 0; r < 4; ++r) {
        int m = m0 + ti * 4 + r;
        float bi = BIAS_RES ? bias[m] : 0.f;
        float o0 = acc[r][0] + bi, o1 = acc[r][1] + bi;
        float o2 = acc[r][2] + bi, o3 = acc[r][3] + bi;
        if (BIAS_RES) {
            float4 rv = *(const float4*)(res + (size_t)(b * M + m) * HW_ + n0 + tj * 4);
            o0 += rv.x; o1 += rv.y; o2 += rv.z; o3 += rv.w;
        }
        if constexpr (OUT_BF16) {
            ushort* Ob = (ushort*)Out + (size_t)b * M * HW_;
            ushort4 o;
            o.x = f2bf(o0); o.y = f2bf(o1); o.z = f2bf(o2); o.w = f2bf(o3);
            *(ushort4*)(Ob + (size_t)m * HW_ + n0 + tj * 4) = o;
        } else {
            float* Ob = (float*)Out + (size_t)b * M * HW_;
            float4 o; o.x = o0; o.y = o1; o.z = o2; o.w = o3;
            *(float4*)(Ob + (size_t)m * HW_ + n0 + tj * 4) = o;
        }
    }
}

// ---------------- transpose Q,K:  [dh][n] bf16 -> [n][dh] bf16 -------------
// z=0: Q (scaled by (1/32)*log2(e));  z=1: K.   grid (HW/64, B*H, 2)
__global__ __launch_bounds__(256) void transpose_qk(const ushort* __restrict__ qkv,
                                                    ushort* __restrict__ qt,
                                                    ushort* __restrict__ kt) {
    __shared__ __align__(16) ushort Ts[64 * 72];
    int n0 = blockIdx.x * 64;
    int bh = blockIdx.y;
    int b = bh >> 2, h = bh & 3;
    int z = blockIdx.z;
    const ushort* src = qkv + ((size_t)b * 3 * C_ + (size_t)z * C_ + h * DH_) * HW_;
    ushort* dst = (z ? kt : qt) + (size_t)bh * HW_ * DH_;
    const float qscale = 0.045157271f;   // (1/32) * log2(e)
    int t = threadIdx.x;
    int n4 = t & 15, dr = t >> 4;
#pragma unroll
    for (int dt = 0; dt < 4; ++dt) {
        int d = dr + 16 * dt;
        ushort4 v = *(const ushort4*)(src + (size_t)d * HW_ + n0 + n4 * 4);
        if (z == 0) {
            v.x = f2bf(bf2f(v.x) * qscale);
            v.y = f2bf(bf2f(v.y) * qscale);
            v.z = f2bf(bf2f(v.z) * qscale);
            v.w = f2bf(bf2f(v.w) * qscale);
        }
        ushort e[4] = {v.x, v.y, v.z, v.w};
#pragma unroll
        for (int k = 0; k < 4; ++k) {
            int n = n4 * 4 + k;
            Ts[n * 72 + (((d >> 3) ^ ((n >> 2) & 7)) << 3) + (d & 7)] = e[k];
        }
    }
    __syncthreads();
#pragma unroll
    for (int nt = 0; nt < 2; ++nt) {
        int n = (t >> 3) + 32 * nt, d8 = t & 7;
        uint4 val = *(const uint4*)&Ts[n * 72 + ((d8 ^ ((n >> 2) & 7)) << 3)];
        *(uint4*)(dst + (size_t)(n0 + n) * DH_ + d8 * 8) = val;
    }
}

// ---------------- MFMA flash attention, software-pipelined -----------------
// grid 1024 linear (XCD-swizzled), 256 thr = 4 indep waves, no barriers.
__global__ __launch_bounds__(256) void flash_attn_mfma(const ushort* __restrict__ qt,
                                                       const ushort* __restrict__ kt,
                                                       const ushort* __restrict__ qkv,
                                                       float* __restrict__ att) {
    __shared__ __align__(16) ushort Pt[64 * 72];   // [i_local][j] bf16
    // bijective XCD swizzle: 1024 blocks -> XCD x gets wg in [x*128,(x+1)*128)
    int bid = blockIdx.x;
    int wg = (bid & 7) * 128 + (bid >> 3);
    int bh = wg >> 6;                // 0..15  (2 bh per XCD -> 2MB K/V in L2)
    int i0 = (wg & 63) * 64;
    int b = bh >> 2, h = bh & 3;
    int t = threadIdx.x;
    int w = t >> 6, lane = t & 63, l16 = lane & 15, lg = lane >> 4;
    const ushort* qtb = qt + (size_t)bh * HW_ * DH_;
    const ushort* ktb = kt + (size_t)bh * HW_ * DH_;
    const ushort* vb  = qkv + ((size_t)b * 3 * C_ + 2 * C_ + (size_t)h * DH_) * HW_;

    int irow = i0 + 16 * w + l16;            // this lane's i (B-frag col)
    short8 qf[2];
#pragma unroll
    for (int ks = 0; ks < 2; ++ks)
        qf[ks] = *(const short8*)(qtb + (size_t)irow * DH_ + 32 * ks + 8 * lg);

    f32x4 O[4];
#pragma unroll
    for (int dt = 0; dt < 4; ++dt)
#pragma unroll
        for (int r = 0; r < 4; ++r) O[dt][r] = 0.f;
    float m = -1e30f, l = 0.f;

    ushort* Prow = &Pt[(16 * w + l16) * 72];

    auto loadK = [&](short8 kf[4][2], int j0) {
#pragma unroll
        for (int jt = 0; jt < 4; ++jt)
#pragma unroll
            for (int ks = 0; ks < 2; ++ks)
                kf[jt][ks] = *(const short8*)(ktb + (size_t)(j0 + 16 * jt + l16) * DH_ + 32 * ks + 8 * lg);
    };

    auto tile = [&](short8 kf[4][2], int j0) {
        // ---- S^T = K · Q --------------------------------------------------
        f32x4 S[4];
#pragma unroll
        for (int jt = 0; jt < 4; ++jt) {
#pragma unroll
            for (int r = 0; r < 4; ++r) S[jt][r] = 0.f;
            S[jt] = __builtin_amdgcn_mfma_f32_16x16x32_bf16(kf[jt][0], qf[0], S[jt], 0, 0, 0);
            S[jt] = __builtin_amdgcn_mfma_f32_16x16x32_bf16(kf[jt][1], qf[1], S[jt], 0, 0, 0);
        }
        // ---- issue V loads now; consumed after softmax (latency covered) --
        short8 vf[4][2];
#pragma unroll
        for (int dt = 0; dt < 4; ++dt)
#pragma unroll
            for (int ks = 0; ks < 2; ++ks)
                vf[dt][ks] = *(const short8*)(vb + (size_t)(16 * dt + l16) * HW_ + j0 + 32 * ks + 8 * lg);

        // ---- online softmax (log2 domain), defer-max rescale --------------
        float mx = S[0][0];
#pragma unroll
        for (int jt = 0; jt < 4; ++jt)
#pragma unroll
            for (int r = 0; r < 4; ++r) mx = fmaxf(mx, S[jt][r]);
        mx = fmaxf(mx, __shfl_xor(mx, 16, 64));
        mx = fmaxf(mx, __shfl_xor(mx, 32, 64));
        if (!__all(mx <= m + 8.f)) {          // T13: skip rescale when max stable
            float mn = fmaxf(m, mx);
            float alpha = __builtin_amdgcn_exp2f(m - mn);
            l *= alpha;
            m = mn;
#pragma unroll
            for (int dt = 0; dt < 4; ++dt)
#pragma unroll
                for (int r = 0; r < 4; ++r) O[dt][r] *= alpha;
        }
        float rs = 0.f;
#pragma unroll
        for (int jt = 0; jt < 4; ++jt)
#pragma unroll
            for (int r = 0; r < 4; ++r) {
                S[jt][r] = __builtin_amdgcn_exp2f(S[jt][r] - m);
                rs += S[jt][r];
            }
        rs += __shfl_xor(rs, 16, 64);
        rs += __shfl_xor(rs, 32, 64);
        l += rs;

        // ---- P^T -> LDS (packed b64 writes) -------------------------------
#pragma unroll
        for (int jt = 0; jt < 4; ++jt) {
            ushort4 pk;
            pk.x = f2bf(S[jt][0]); pk.y = f2bf(S[jt][1]);
            pk.z = f2bf(S[jt][2]); pk.w = f2bf(S[jt][3]);
            *(ushort4*)(Prow + 16 * jt + 4 * lg) = pk;
        }
        short8 pf[2];
#pragma unroll
        for (int ks = 0; ks < 2; ++ks)
            pf[ks] = *(const short8*)(Prow + 32 * ks + 8 * lg);

        // ---- O^T += V^T · P^T ---------------------------------------------
#pragma unroll
        for (int dt = 0; dt < 4; ++dt) {
            O[dt] = __builtin_amdgcn_mfma_f32_16x16x32_bf16(vf[dt][0], pf[0], O[dt], 0, 0, 0);
            O[dt] = __builtin_amdgcn_mfma_f32_16x16x32_bf16(vf[dt][1], pf[1], O[dt], 0, 0, 0);
        }
    };

    short8 kA[4][2], kB[4][2];
    loadK(kA, 0);
    for (int j0 = 0; j0 < HW_; j0 += 128) {
        loadK(kB, j0 + 64);                    // prefetch: covered by tile(kA)
        tile(kA, j0);
        int jn = j0 + 128;
        if (jn >= HW_) jn = 0;                 // clamp (dummy prefetch, unused)
        loadK(kA, jn);                         // prefetch: covered by tile(kB)
        tile(kB, j0 + 64);
    }

    // ---- epilogue: O^T layout == att [c][n] layout; direct stores --------
    float inv = 1.f / l;
    float* ab = att + ((size_t)b * C_ + (size_t)h * DH_) * HW_ + i0 + 16 * w + l16;
#pragma unroll
    for (int dt = 0; dt < 4; ++dt)
#pragma unroll
        for (int r = 0; r < 4; ++r)
            ab[(size_t)(16 * dt + 4 * lg + r) * HW_] = O[dt][r] * inv;
}

extern "C" void kernel_launch(void* const* d_in, const int* in_sizes, int n_in,
                              void* d_out, int out_size, void* d_ws, size_t ws_size,
                              hipStream_t stream) {
    const float* x        = (const float*)d_in[0];
    const float* gn_gamma = (const float*)d_in[1];
    const float* gn_beta  = (const float*)d_in[2];
    const float* w_qkv    = (const float*)d_in[3];
    const float* w_proj   = (const float*)d_in[4];
    const float* b_proj   = (const float*)d_in[5];
    float* out = (float*)d_out;
    float* ws  = (float*)d_ws;

    float*  xn   = ws;
    ushort* qkv  = (ushort*)(ws + XN_SZ);
    float*  att  = ws + XN_SZ + QKV_SZ / 2;
    ushort* qt   = (ushort*)(att + ATT_SZ);
    ushort* kt   = qt + QT_SZ;
    float*  part = (float*)(kt + QT_SZ);

    gn_partial<<<dim3(G_ * B_ * NCHUNK), 256, 0, stream>>>(x, part);
    gn_norm<<<dim3(B_ * C_), 256, 0, stream>>>(x, gn_gamma, gn_beta, part, xn);
    gemm_wx<false, true><<<dim3(HW_ / 64, (3 * C_) / 64, B_), 256, 0, stream>>>(
        w_qkv, xn, (void*)qkv, nullptr, nullptr, 3 * C_);
    transpose_qk<<<dim3(HW_ / 64, B_ * H_, 2), 256, 0, stream>>>(qkv, qt, kt);
    flash_attn_mfma<<<dim3(64 * 16), 256, 0, stream>>>(qt, kt, qkv, att);
    gemm_wx<true, false><<<dim3(HW_ / 64, C_ / 64, B_), 256, 0, stream>>>(
        w_proj, att, (void*)out, b_proj, x, C_);
}

// Round 4
// 277.214 us; speedup vs baseline: 2.1309x; 2.1309x over previous
//
#include <hip/hip_runtime.h>
#include <math.h>
#include <stdint.h>

#define B_ 4
#define C_ 256
#define HW_ 4096
#define G_ 8
#define H_ 4
#define DH_ 64
#define GRP_ELEMS (32 * HW_)             // 131072
#define NCHUNK 16
#define CHUNK_ELEMS (GRP_ELEMS / NCHUNK) // 8192
#define EPS 1e-5f
#define NT_ (HW_ / 64)                   // 64 j-tiles

typedef __attribute__((ext_vector_type(8))) short short8;
typedef __attribute__((ext_vector_type(4))) float f32x4;
typedef const __attribute__((address_space(1))) uint32_t* gas1_t;
typedef __attribute__((address_space(3))) uint32_t* las3_t;

__device__ __forceinline__ ushort f2bf(float x) {
    unsigned u = __builtin_bit_cast(unsigned, x);
    u += 0x7FFFu + ((u >> 16) & 1u);
    return (ushort)(u >> 16);
}
__device__ __forceinline__ float bf2f(ushort h) {
    unsigned u = ((unsigned)h) << 16;
    return __builtin_bit_cast(float, u);
}

// workspace layout (float-slot offsets)
#define XN_SZ   (B_ * C_ * HW_)          // f32
#define QKV_SZ  (B_ * 3 * C_ * HW_)      // ushort count
#define ATT_SZ  (B_ * C_ * HW_)          // f32
#define QT_SZ   (B_ * C_ * HW_)          // ushort count

// ---------------- GroupNorm stage 1: deterministic partial sums -----------
__global__ __launch_bounds__(256) void gn_partial(const float* __restrict__ x,
                                                  float* __restrict__ part) {
    int bg = blockIdx.x >> 4;
    int chunk = blockIdx.x & 15;
    const float4* p = (const float4*)(x + (size_t)bg * GRP_ELEMS + (size_t)chunk * CHUNK_ELEMS);
    int t = threadIdx.x;
    float s = 0.f, ss = 0.f;
#pragma unroll
    for (int i = 0; i < 8; ++i) {
        float4 v = p[t + i * 256];
        s  += v.x + v.y + v.z + v.w;
        ss += v.x * v.x + v.y * v.y + v.z * v.z + v.w * v.w;
    }
#pragma unroll
    for (int off = 32; off; off >>= 1) {
        s  += __shfl_xor(s, off, 64);
        ss += __shfl_xor(ss, off, 64);
    }
    __shared__ float ls[8];
    int wave = t >> 6, lane = t & 63;
    if (lane == 0) { ls[wave * 2] = s; ls[wave * 2 + 1] = ss; }
    __syncthreads();
    if (t == 0) {
        float S = 0.f, SS = 0.f;
#pragma unroll
        for (int w = 0; w < 4; ++w) { S += ls[w * 2]; SS += ls[w * 2 + 1]; }
        part[(bg * 16 + chunk) * 2]     = S;
        part[(bg * 16 + chunk) * 2 + 1] = SS;
    }
}

// ---------------- GroupNorm stage 2: normalize ----------------------------
__global__ __launch_bounds__(256) void gn_norm(const float* __restrict__ x,
                                               const float* __restrict__ gamma,
                                               const float* __restrict__ beta,
                                               const float* __restrict__ part,
                                               float* __restrict__ xn) {
    int bc = blockIdx.x;
    int b = bc >> 8, ch = bc & 255;
    int g = ch >> 5;
    int bg = b * G_ + g;
    float S = 0.f, SS = 0.f;
#pragma unroll
    for (int i = 0; i < 16; ++i) {
        S  += part[(bg * 16 + i) * 2];
        SS += part[(bg * 16 + i) * 2 + 1];
    }
    float mean = S * (1.f / GRP_ELEMS);
    float var  = SS * (1.f / GRP_ELEMS) - mean * mean;
    float inv  = rsqrtf(var + EPS);
    float a  = inv * gamma[ch];
    float bb = beta[ch] - mean * a;
    const float4* xin = (const float4*)(x + (size_t)bc * HW_);
    float4* xo = (float4*)(xn + (size_t)bc * HW_);
    int t = threadIdx.x;
#pragma unroll
    for (int i = 0; i < 4; ++i) {
        float4 v = xin[t + i * 256];
        v.x = v.x * a + bb; v.y = v.y * a + bb;
        v.z = v.z * a + bb; v.w = v.w * a + bb;
        xo[t + i * 256] = v;
    }
}

// ---------------- fp32 tiled GEMM: Out[b] = W(MxK) @ X[b](K x HW) ----------
template <bool BIAS_RES, bool OUT_BF16>
__global__ __launch_bounds__(256) void gemm_wx(const float* __restrict__ W,
                                               const float* __restrict__ X,
                                               void* __restrict__ Out,
                                               const float* __restrict__ bias,
                                               const float* __restrict__ res,
                                               int M) {
    __shared__ float Ws[64][68];
    __shared__ float Xs[64][68];
    int b  = blockIdx.z;
    int m0 = blockIdx.y * 64;
    int n0 = blockIdx.x * 64;
    const float* Xb = X + (size_t)b * C_ * HW_;
    int t = threadIdx.x;
    int ti = t >> 4, tj = t & 15;
    float acc[4][4] = {};

    for (int kt = 0; kt < 4; ++kt) {
        {
            int row = t >> 4;
            int q4  = t & 15;
#pragma unroll
            for (int it = 0; it < 4; ++it) {
                int mm = row + 16 * it;
                float4 v = *(const float4*)(W + (size_t)(m0 + mm) * C_ + kt * 64 + q4 * 4);
                Ws[q4 * 4 + 0][mm] = v.x;
                Ws[q4 * 4 + 1][mm] = v.y;
                Ws[q4 * 4 + 2][mm] = v.z;
                Ws[q4 * 4 + 3][mm] = v.w;
                int kk = row + 16 * it;
                float4 xv = *(const float4*)(Xb + (size_t)(kt * 64 + kk) * HW_ + n0 + q4 * 4);
                *(float4*)&Xs[kk][q4 * 4] = xv;
            }
        }
        __syncthreads();
#pragma unroll 8
        for (int kk = 0; kk < 64; ++kk) {
            float4 wv = *(const float4*)&Ws[kk][ti * 4];
            float4 xv = *(const float4*)&Xs[kk][tj * 4];
            float wr[4] = {wv.x, wv.y, wv.z, wv.w};
            float xr[4] = {xv.x, xv.y, xv.z, xv.w};
#pragma unroll
            for (int r = 0; r < 4; ++r)
#pragma unroll
                for (int c = 0; c < 4; ++c)
                    acc[r][c] += wr[r] * xr[c];
        }
        __syncthreads();
    }
#pragma unroll
    for (int r = 0; r < 4; ++r) {
        int m = m0 + ti * 4 + r;
        float bi = BIAS_RES ? bias[m] : 0.f;
        float o0 = acc[r][0] + bi, o1 = acc[r][1] + bi;
        float o2 = acc[r][2] + bi, o3 = acc[r][3] + bi;
        if (BIAS_RES) {
            float4 rv = *(const float4*)(res + (size_t)(b * M + m) * HW_ + n0 + tj * 4);
            o0 += rv.x; o1 += rv.y; o2 += rv.z; o3 += rv.w;
        }
        if constexpr (OUT_BF16) {
            ushort* Ob = (ushort*)Out + (size_t)b * M * HW_;
            ushort4 o;
            o.x = f2bf(o0); o.y = f2bf(o1); o.z = f2bf(o2); o.w = f2bf(o3);
            *(ushort4*)(Ob + (size_t)m * HW_ + n0 + tj * 4) = o;
        } else {
            float* Ob = (float*)Out + (size_t)b * M * HW_;
            float4 o; o.x = o0; o.y = o1; o.z = o2; o.w = o3;
            *(float4*)(Ob + (size_t)m * HW_ + n0 + tj * 4) = o;
        }
    }
}

// ---------------- transpose Q,K:  [dh][n] bf16 -> [n][dh] bf16 -------------
__global__ __launch_bounds__(256) void transpose_qk(const ushort* __restrict__ qkv,
                                                    ushort* __restrict__ qt,
                                                    ushort* __restrict__ kt) {
    __shared__ __align__(16) ushort Ts[64 * 72];
    int n0 = blockIdx.x * 64;
    int bh = blockIdx.y;
    int b = bh >> 2, h = bh & 3;
    int z = blockIdx.z;
    const ushort* src = qkv + ((size_t)b * 3 * C_ + (size_t)z * C_ + h * DH_) * HW_;
    ushort* dst = (z ? kt : qt) + (size_t)bh * HW_ * DH_;
    const float qscale = 0.045157271f;   // (1/32) * log2(e)
    int t = threadIdx.x;
    int n4 = t & 15, dr = t >> 4;
#pragma unroll
    for (int dt = 0; dt < 4; ++dt) {
        int d = dr + 16 * dt;
        ushort4 v = *(const ushort4*)(src + (size_t)d * HW_ + n0 + n4 * 4);
        if (z == 0) {
            v.x = f2bf(bf2f(v.x) * qscale);
            v.y = f2bf(bf2f(v.y) * qscale);
            v.z = f2bf(bf2f(v.z) * qscale);
            v.w = f2bf(bf2f(v.w) * qscale);
        }
        ushort e[4] = {v.x, v.y, v.z, v.w};
#pragma unroll
        for (int k = 0; k < 4; ++k) {
            int n = n4 * 4 + k;
            Ts[n * 72 + (((d >> 3) ^ ((n >> 2) & 7)) << 3) + (d & 7)] = e[k];
        }
    }
    __syncthreads();
#pragma unroll
    for (int nt = 0; nt < 2; ++nt) {
        int n = (t >> 3) + 32 * nt, d8 = t & 7;
        uint4 val = *(const uint4*)&Ts[n * 72 + ((d8 ^ ((n >> 2) & 7)) << 3)];
        *(uint4*)(dst + (size_t)(n0 + n) * DH_ + d8 * 8) = val;
    }
}

// ---------------- MFMA flash attention, LDS-staged K/V, 2-phase ------------
// grid 512 (XCD-swizzled): 16 bh x 32 i-tiles of 128 rows. 256 thr = 4 waves,
// each wave owns 32 Q-rows (2 strips of 16). K/V staged via global_load_lds
// (dbuf, XOR-swizzled source cols), shared by all 4 waves.
__global__ __launch_bounds__(256) void flash_attn_mfma(const ushort* __restrict__ qt,
                                                       const ushort* __restrict__ kt,
                                                       const ushort* __restrict__ qkv,
                                                       float* __restrict__ att) {
    __shared__ __align__(16) ushort Kb[2][64 * 64];   // [j][dh], cols swizzled
    __shared__ __align__(16) ushort Vb[2][64 * 64];   // [d][j],  cols swizzled
    __shared__ __align__(16) ushort Pt[128 * 72];     // [i_local][j]

    int bid = blockIdx.x;
    int wg = (bid & 7) * 64 + (bid >> 3);   // bijective: XCD x -> wg [64x,64x+64)
    int bh = wg >> 5;                        // 2 bh per XCD -> 2MB K/V in its L2
    int i0 = (wg & 31) * 128;
    int b = bh >> 2, h = bh & 3;
    int t = threadIdx.x;
    int w = t >> 6, lane = t & 63, l16 = lane & 15, lg = lane >> 4;
    const ushort* qtb = qt + (size_t)bh * HW_ * DH_;
    const ushort* ktb = kt + (size_t)bh * HW_ * DH_;
    const ushort* vb  = qkv + ((size_t)b * 3 * C_ + 2 * C_ + (size_t)h * DH_) * HW_;

    // Q fragments: 2 strips of 16 rows per wave
    short8 qf[2][2];
#pragma unroll
    for (int s = 0; s < 2; ++s)
#pragma unroll
        for (int ks = 0; ks < 2; ++ks)
            qf[s][ks] = *(const short8*)(qtb + (size_t)(i0 + 32 * w + 16 * s + l16) * DH_ + 32 * ks + 8 * lg);

    f32x4 O0[4], O1[4];
#pragma unroll
    for (int dt = 0; dt < 4; ++dt)
#pragma unroll
        for (int r = 0; r < 4; ++r) { O0[dt][r] = 0.f; O1[dt][r] = 0.f; }
    float m0v = -1e30f, l0v = 0.f, m1v = -1e30f, l1v = 0.f;

    ushort* Prow0 = &Pt[(32 * w + l16) * 72];
    ushort* Prow1 = &Pt[(32 * w + 16 + l16) * 72];

    // stage K/V tile j0 into buffer bi: wave w loads rows [16w,16w+16)
    int r8 = lane >> 3, ch8 = lane & 7;      // 8 rows x 8 chunks(16B) per instr
    auto stage = [&](int bi, int j0) {
#pragma unroll
        for (int half = 0; half < 2; ++half) {
            int row = 16 * w + half * 8 + r8;
            const ushort* srck = ktb + (size_t)(j0 + row) * DH_ + ((ch8 ^ (row & 7)) << 3);
            __builtin_amdgcn_global_load_lds((gas1_t)srck,
                (las3_t)&Kb[bi][(16 * w + half * 8) * 64], 16, 0, 0);
            const ushort* srcv = vb + (size_t)row * HW_ + j0 + ((ch8 ^ (row & 7)) << 3);
            __builtin_amdgcn_global_load_lds((gas1_t)srcv,
                (las3_t)&Vb[bi][(16 * w + half * 8) * 64], 16, 0, 0);
        }
    };

    auto softmax_p = [&](f32x4* S, float& m, float& l, f32x4* O, ushort* Prow) {
        float mx = S[0][0];
#pragma unroll
        for (int jt = 0; jt < 4; ++jt)
#pragma unroll
            for (int r = 0; r < 4; ++r) mx = fmaxf(mx, S[jt][r]);
        mx = fmaxf(mx, __shfl_xor(mx, 16, 64));
        mx = fmaxf(mx, __shfl_xor(mx, 32, 64));
        if (!__all(mx <= m + 8.f)) {
            float mn = fmaxf(m, mx);
            float alpha = __builtin_amdgcn_exp2f(m - mn);
            l *= alpha;
            m = mn;
#pragma unroll
            for (int dt = 0; dt < 4; ++dt)
#pragma unroll
                for (int r = 0; r < 4; ++r) O[dt][r] *= alpha;
        }
        float rs = 0.f;
#pragma unroll
        for (int jt = 0; jt < 4; ++jt) {
            ushort4 pk;
#pragma unroll
            for (int r = 0; r < 4; ++r) {
                S[jt][r] = __builtin_amdgcn_exp2f(S[jt][r] - m);
                rs += S[jt][r];
            }
            pk.x = f2bf(S[jt][0]); pk.y = f2bf(S[jt][1]);
            pk.z = f2bf(S[jt][2]); pk.w = f2bf(S[jt][3]);
            *(ushort4*)(Prow + 16 * jt + 4 * lg) = pk;
        }
        rs += __shfl_xor(rs, 16, 64);
        rs += __shfl_xor(rs, 32, 64);
        l += rs;
    };

    stage(0, 0);
    asm volatile("s_waitcnt vmcnt(0)" ::: "memory");
    __builtin_amdgcn_s_barrier();

    int cur = 0;
    for (int t8 = 0; t8 < NT_; ++t8) {
        if (t8 + 1 < NT_) stage(cur ^ 1, (t8 + 1) * 64);

        // ---- S^T = K · Q, both strips (K frags read once) ----------------
        f32x4 S0[4], S1[4];
#pragma unroll
        for (int jt = 0; jt < 4; ++jt) {
#pragma unroll
            for (int r = 0; r < 4; ++r) { S0[jt][r] = 0.f; S1[jt][r] = 0.f; }
#pragma unroll
            for (int ks = 0; ks < 2; ++ks) {
                short8 kf = *(const short8*)&Kb[cur][(16 * jt + l16) * 64 +
                                                     (((4 * ks + lg) ^ (l16 & 7)) << 3)];
                S0[jt] = __builtin_amdgcn_mfma_f32_16x16x32_bf16(kf, qf[0][ks], S0[jt], 0, 0, 0);
                S1[jt] = __builtin_amdgcn_mfma_f32_16x16x32_bf16(kf, qf[1][ks], S1[jt], 0, 0, 0);
            }
        }

        softmax_p(S0, m0v, l0v, O0, Prow0);
        softmax_p(S1, m1v, l1v, O1, Prow1);

        short8 pf0[2], pf1[2];
#pragma unroll
        for (int ks = 0; ks < 2; ++ks) {
            pf0[ks] = *(const short8*)(Prow0 + 32 * ks + 8 * lg);
            pf1[ks] = *(const short8*)(Prow1 + 32 * ks + 8 * lg);
        }

        // ---- O^T += V^T · P^T, both strips (V frags read once) ------------
#pragma unroll
        for (int dt = 0; dt < 4; ++dt) {
#pragma unroll
            for (int ks = 0; ks < 2; ++ks) {
                short8 vf = *(const short8*)&Vb[cur][(16 * dt + l16) * 64 +
                                                     (((4 * ks + lg) ^ (l16 & 7)) << 3)];
                O0[dt] = __builtin_amdgcn_mfma_f32_16x16x32_bf16(vf, pf0[ks], O0[dt], 0, 0, 0);
                O1[dt] = __builtin_amdgcn_mfma_f32_16x16x32_bf16(vf, pf1[ks], O1[dt], 0, 0, 0);
            }
        }

        asm volatile("s_waitcnt vmcnt(0)" ::: "memory");
        __builtin_amdgcn_s_barrier();
        cur ^= 1;
    }

    // ---- epilogue: O^T layout == att [c][n] layout ------------------------
    float inv0 = 1.f / l0v, inv1 = 1.f / l1v;
    float* ab0 = att + ((size_t)b * C_ + (size_t)h * DH_) * HW_ + i0 + 32 * w + l16;
    float* ab1 = ab0 + 16;
#pragma unroll
    for (int dt = 0; dt < 4; ++dt)
#pragma unroll
        for (int r = 0; r < 4; ++r) {
            ab0[(size_t)(16 * dt + 4 * lg + r) * HW_] = O0[dt][r] * inv0;
            ab1[(size_t)(16 * dt + 4 * lg + r) * HW_] = O1[dt][r] * inv1;
        }
}

extern "C" void kernel_launch(void* const* d_in, const int* in_sizes, int n_in,
                              void* d_out, int out_size, void* d_ws, size_t ws_size,
                              hipStream_t stream) {
    const float* x        = (const float*)d_in[0];
    const float* gn_gamma = (const float*)d_in[1];
    const float* gn_beta  = (const float*)d_in[2];
    const float* w_qkv    = (const float*)d_in[3];
    const float* w_proj   = (const float*)d_in[4];
    const float* b_proj   = (const float*)d_in[5];
    float* out = (float*)d_out;
    float* ws  = (float*)d_ws;

    float*  xn   = ws;
    ushort* qkv  = (ushort*)(ws + XN_SZ);
    float*  att  = ws + XN_SZ + QKV_SZ / 2;
    ushort* qt   = (ushort*)(att + ATT_SZ);
    ushort* kt   = qt + QT_SZ;
    float*  part = (float*)(kt + QT_SZ);

    gn_partial<<<dim3(G_ * B_ * NCHUNK), 256, 0, stream>>>(x, part);
    gn_norm<<<dim3(B_ * C_), 256, 0, stream>>>(x, gn_gamma, gn_beta, part, xn);
    gemm_wx<false, true><<<dim3(HW_ / 64, (3 * C_) / 64, B_), 256, 0, stream>>>(
        w_qkv, xn, (void*)qkv, nullptr, nullptr, 3 * C_);
    transpose_qk<<<dim3(HW_ / 64, B_ * H_, 2), 256, 0, stream>>>(qkv, qt, kt);
    flash_attn_mfma<<<dim3(512), 256, 0, stream>>>(qt, kt, qkv, att);
    gemm_wx<true, false><<<dim3(HW_ / 64, C_ / 64, B_), 256, 0, stream>>>(
        w_proj, att, (void*)out, b_proj, x, C_);
}